// Round 10
// baseline (112.851 us; speedup 1.0000x reference)
//
#include <hip/hip_runtime.h>

// Problem constants (match reference)
#define B_    128
#define G_    12000
#define GP    12288     // G padded to 12*1024 (pad rows are zero => exact)
#define K_    512
#define H_    64
#define NSEG  24        // GEMM split-K segments
#define SEGG  512       // genes per segment
#define BKT   64        // GEMM K-step

typedef __attribute__((ext_vector_type(8))) short bf16x8;
typedef __attribute__((ext_vector_type(4))) float f32x4;

__device__ __forceinline__ unsigned short f2bf(float x) {
    union { float f; unsigned u; } v; v.f = x;
    unsigned r = (v.u + 0x7FFFu + ((v.u >> 16) & 1u)) >> 16;
    return (unsigned short)r;
}
__device__ __forceinline__ float bf2f(unsigned short b) {
    union { float f; unsigned u; } v; v.u = ((unsigned)b) << 16;
    return v.f;
}

// ---------------- mm body: O = alpha*Aop*Bop + beta*Cop; opt O2 = O + Dop ---
// 32x32 out tile at (k0,l0), BK=64, 256 threads, 2x2 micro. sm: 4480 floats.
__device__ __forceinline__ void mm_body(int k0, int l0, float* __restrict__ sm,
        const float* __restrict__ Aop, const float* __restrict__ Bop,
        const float* __restrict__ Cop, const float* __restrict__ Dop,
        float alpha, float beta, float* __restrict__ O, float* __restrict__ O2) {
    float (*Xa)[68] = (float(*)[68])sm;              // 32*68 = 2176 floats
    float (*Xb)[36] = (float(*)[36])(sm + 2176);     // 64*36 = 2304 floats
    int tid = threadIdx.x;
    int kg = tid & 15, lg = tid >> 4;
    float acc[2][2] = {};
    for (int jj = 0; jj < K_; jj += 64) {
#pragma unroll
        for (int i = 0; i < 2; ++i) {
            int lin = tid + i * 256;
            int r = lin >> 4, c4 = lin & 15;
            *(float4*)&Xa[r][c4 * 4] =
                *(const float4*)&Aop[(size_t)(l0 + r) * K_ + jj + c4 * 4];
        }
#pragma unroll
        for (int i = 0; i < 2; ++i) {
            int lin = tid + i * 256;
            int r = lin >> 3, c4 = lin & 7;
            *(float4*)&Xb[r][c4 * 4] =
                *(const float4*)&Bop[(size_t)(jj + r) * K_ + k0 + c4 * 4];
        }
        __syncthreads();
#pragma unroll 8
        for (int j = 0; j < 64; ++j) {
            float xa0 = Xa[lg * 2][j], xa1 = Xa[lg * 2 + 1][j];
            float xb0 = Xb[j][kg * 2], xb1 = Xb[j][kg * 2 + 1];
            acc[0][0] = fmaf(xa0, xb0, acc[0][0]);
            acc[0][1] = fmaf(xa0, xb1, acc[0][1]);
            acc[1][0] = fmaf(xa1, xb0, acc[1][0]);
            acc[1][1] = fmaf(xa1, xb1, acc[1][1]);
        }
        __syncthreads();
    }
#pragma unroll
    for (int i = 0; i < 2; ++i) {
        size_t idx = (size_t)(l0 + lg * 2 + i) * K_ + k0 + kg * 2;
        float2 v;
        v.x = alpha * acc[i][0];
        v.y = alpha * acc[i][1];
        if (beta != 0.0f) {
            float2 cc = *(const float2*)&Cop[idx];
            v.x = fmaf(beta, cc.x, v.x);
            v.y = fmaf(beta, cc.y, v.y);
        }
        *(float2*)&O[idx] = v;
        if (O2) {
            float2 dd = *(const float2*)&Dop[idx];
            float2 w2; w2.x = v.x + dd.x; w2.y = v.y + dd.y;
            *(float2*)&O2[idx] = w2;
        }
    }
}

// ========== L1 k_pre: {XpT bf16 (hi only) | MTb+Mb 64x64 tiles + deg |
//                       AT,U2 | cvec} ======================================
__global__ __launch_bounds__(256) void k_pre(
        const float* __restrict__ ctl, const float* __restrict__ dt,
        const float* __restrict__ M, const float* __restrict__ A,
        const int* __restrict__ cidx, const float* __restrict__ cemb,
        const float* __restrict__ W_out, const float* __restrict__ b_out,
        unsigned short* __restrict__ XpT, unsigned short* __restrict__ MTb,
        unsigned short* __restrict__ Mb, int* __restrict__ deg,
        float* __restrict__ AT, float* __restrict__ U2,
        float* __restrict__ cvec) {
    int bid = blockIdx.x, tid = threadIdx.x;
    if (bid < 3072) {                          // XpT hi plane: 256 rows x GP
        int p = bid / 12, chunk = bid % 12;    // p: ch*128 + b
        int ch = p >> 7, b = p & 127;
        const float* src = (ch ? dt : ctl) + (size_t)b * G_;
        int g = chunk * 1024 + tid * 4;
        float x0 = 0.f, x1 = 0.f, x2 = 0.f, x3 = 0.f;
        if (g + 3 < G_) {
            float4 v = *(const float4*)&src[g];
            x0 = v.x; x1 = v.y; x2 = v.z; x3 = v.w;
        } else {
            if (g + 0 < G_) x0 = src[g + 0];
            if (g + 1 < G_) x1 = src[g + 1];
            if (g + 2 < G_) x2 = src[g + 2];
            if (g + 3 < G_) x3 = src[g + 3];
        }
        ushort4 hv;
        hv.x = f2bf(x0); hv.y = f2bf(x1); hv.z = f2bf(x2); hv.w = f2bf(x3);
        *(ushort4*)&XpT[(size_t)p * GP + g] = hv;
    } else if (bid < 4608) {                   // M 64x64 tile: Mb + MTb + deg
        __shared__ float t[64][65];
        __shared__ int csum[4][64];
        int id = bid - 3072;                   // 0..1535
        int gt = id % 192, kt = id / 192;      // 192 g-tiles x 8 k-tiles
        int g0 = gt * 64, k0 = kt * 64;
        int tx = tid & 63, ty = tid >> 6;      // 64 x 4
        int cnt = 0;
#pragma unroll
        for (int j = 0; j < 16; ++j) {
            int g = g0 + ty + 4 * j;
            float v = (g < G_) ? M[(size_t)g * K_ + k0 + tx] : 0.0f;
            t[ty + 4 * j][tx] = v;
            Mb[(size_t)g * K_ + k0 + tx] = f2bf(v);
            cnt += (v != 0.0f);
        }
        csum[ty][tx] = cnt;
        __syncthreads();
        if (ty == 0)
            atomicAdd(&deg[k0 + tx],
                      csum[0][tx] + csum[1][tx] + csum[2][tx] + csum[3][tx]);
#pragma unroll
        for (int j = 0; j < 16; ++j)
            MTb[(size_t)(k0 + ty + 4 * j) * GP + g0 + tx] =
                f2bf(t[tx][ty + 4 * j]);
    } else if (bid < 4864) {                   // AT + U2 = 0.09*AT + 0.1*I
        __shared__ float t[32][33];
        int id = bid - 4608;
        int x0 = (id & 15) * 32, y0 = (id >> 4) * 32;
        int tx = tid & 31, ty = tid >> 5;
#pragma unroll
        for (int j = 0; j < 4; ++j)
            t[ty + 8 * j][tx] = A[(size_t)(y0 + ty + 8 * j) * K_ + x0 + tx];
        __syncthreads();
#pragma unroll
        for (int j = 0; j < 4; ++j) {
            int row = x0 + ty + 8 * j, col = y0 + tx;
            float v = t[tx][ty + 8 * j];
            AT[(size_t)row * K_ + col] = v;
            U2[(size_t)row * K_ + col] = 0.09f * v + (row == col ? 0.1f : 0.0f);
        }
    } else {                                   // cvec
        if (tid < B_) {
            int ci = cidx[tid];
            float acc = b_out[0];
#pragma unroll 8
            for (int h = 0; h < H_; ++h)
                acc = fmaf(cemb[ci * H_ + h], W_out[h], acc);
            cvec[tid] = acc;
        }
    }
}

// ========== L2 k_gemm: {Cp[seg] = MTb*XpT^T (MFMA, split-K 24) | P1 mm} =====
__global__ __launch_bounds__(256) void k_gemm(
        const unsigned short* __restrict__ MTb, const unsigned short* __restrict__ XpT,
        float* __restrict__ Cp,
        const float* __restrict__ AT, const float* __restrict__ U2,
        float* __restrict__ M2, float* __restrict__ Yop) {
    __shared__ __align__(16) char smraw[36864];
    int bid = blockIdx.x, tid = threadIdx.x;
    if (bid < 192) {
        unsigned short (*Al)[72] = (unsigned short(*)[72])smraw;           // 128x72
        unsigned short (*Bl)[72] = (unsigned short(*)[72])(smraw + 18432); // 128x72
        int tile = bid & 7, seg = bid >> 3;    // 4 m-tiles x 2 n-tiles, 24 segs
        int m0 = (tile & 3) * 128, n0 = (tile >> 2) * 128;
        size_t gbase = (size_t)seg * SEGG;
        int wid = tid >> 6, lane = tid & 63;
        int wm = (wid >> 1) * 64, wn = (wid & 1) * 64;
        int r16 = lane & 15, kg8 = (lane >> 4) * 8;
        int ld_row = tid >> 3, ld_c8 = (tid & 7) * 8;
        f32x4 acc[4][4] = {};
        for (int kk = 0; kk < SEGG; kk += BKT) {
#pragma unroll
            for (int i = 0; i < 4; ++i) {
                int r = ld_row + 32 * i;
                *(uint4*)&Al[r][ld_c8] =
                    *(const uint4*)&MTb[(size_t)(m0 + r) * GP + gbase + kk + ld_c8];
                *(uint4*)&Bl[r][ld_c8] =
                    *(const uint4*)&XpT[(size_t)(n0 + r) * GP + gbase + kk + ld_c8];
            }
            __syncthreads();
#pragma unroll
            for (int ks = 0; ks < 2; ++ks) {
                bf16x8 af[4], bf[4];
#pragma unroll
                for (int mi = 0; mi < 4; ++mi)
                    af[mi] = *(const bf16x8*)&Al[wm + mi * 16 + r16][ks * 32 + kg8];
#pragma unroll
                for (int ni = 0; ni < 4; ++ni)
                    bf[ni] = *(const bf16x8*)&Bl[wn + ni * 16 + r16][ks * 32 + kg8];
#pragma unroll
                for (int mi = 0; mi < 4; ++mi)
#pragma unroll
                    for (int ni = 0; ni < 4; ++ni)
                        acc[mi][ni] = __builtin_amdgcn_mfma_f32_16x16x32_bf16(
                            af[mi], bf[ni], acc[mi][ni], 0, 0, 0);
            }
            __syncthreads();
        }
        float* C = Cp + (size_t)seg * (K_ * 256);
        int cr = (lane >> 4) * 4, cc = lane & 15;
#pragma unroll
        for (int mi = 0; mi < 4; ++mi)
#pragma unroll
            for (int ni = 0; ni < 4; ++ni) {
                size_t rb = (size_t)(m0 + wm + mi * 16 + cr) * 256
                          + (n0 + wn + ni * 16 + cc);
#pragma unroll
                for (int r = 0; r < 4; ++r)
                    C[rb + (size_t)r * 256] = acc[mi][ni][r];
            }
    } else {                                   // P1: M2 = 0.81*AT*AT; Yop = M2+U2
        int id = bid - 192;
        mm_body((id & 15) * 32, (id >> 4) * 32, (float*)smraw,
                AT, AT, nullptr, U2, 0.81f, 0.0f, M2, Yop);
    }
}

// ========== L3 k_red: {reduce Cp + deg + MLP -> sout | P2: M4, U4} ==========
__global__ __launch_bounds__(256) void k_red(
        const float* __restrict__ Cp, const int* __restrict__ deg,
        const float* __restrict__ W_in, const float* __restrict__ b_in,
        const float* __restrict__ W_out, float* __restrict__ sout,
        const float* __restrict__ M2, const float* __restrict__ U2,
        float* __restrict__ M4, float* __restrict__ U4) {
    __shared__ __align__(16) float sm[4480];
    int bid = blockIdx.x, tid = threadIdx.x;
    if (bid < 256) {
        int kloc = tid >> 7, b = tid & 127;
        int k = bid * 2 + kloc;
        float x0 = 0.f, x1 = 0.f;
#pragma unroll 4
        for (int s = 0; s < NSEG; ++s) {
            const float* Cb = Cp + (size_t)s * (K_ * 256) + (size_t)k * 256;
            x0 += Cb[b];
            x1 += Cb[128 + b];
        }
        float inv = 1.0f / fmaxf((float)deg[k], 1.0f);
        x0 *= inv; x1 *= inv;
        float s = 0.f;
#pragma unroll 8
        for (int h = 0; h < H_; ++h) {
            float v = fmaf(x0, W_in[h], fmaf(x1, W_in[H_ + h], b_in[h]));
            v = fmaxf(v, 0.f);
            s = fmaf(v, W_out[h], s);
        }
        sout[k * B_ + b] = s;
    } else {                                   // P2: M4 = M2*M2; U4 = M2*U2+U2
        int id = bid - 256;
        int t = id & 255;
        if (id < 256)
            mm_body((t & 15) * 32, (t >> 4) * 32, sm, M2, M2, nullptr, nullptr,
                    1.0f, 0.0f, M4, nullptr);
        else
            mm_body((t & 15) * 32, (t >> 4) * 32, sm, M2, U2, U2, nullptr,
                    1.0f, 1.0f, U4, nullptr);
    }
}

// ========== L4 k_p3: {P3: M8 = M4*M4, U8 = M4*U4+U4 | panel q = Yop*s} ======
__global__ __launch_bounds__(256) void k_p3(
        const float* __restrict__ M4, const float* __restrict__ U4,
        float* __restrict__ M8, float* __restrict__ U8,
        const float* __restrict__ Yop, const float* __restrict__ sout,
        float* __restrict__ q) {
    __shared__ __align__(16) float sm[4480];
    int bid = blockIdx.x, tid = threadIdx.x;
    if (bid < 512) {
        int t = bid & 255;
        if (bid < 256)
            mm_body((t & 15) * 32, (t >> 4) * 32, sm, M4, M4, nullptr, nullptr,
                    1.0f, 0.0f, M8, nullptr);
        else
            mm_body((t & 15) * 32, (t >> 4) * 32, sm, M4, U4, U4, nullptr,
                    1.0f, 1.0f, U8, nullptr);
    } else {                                   // q[l][b] = sum_k Yop[l][k] s[k][b]
        int l = bid - 512;                     // 0..511
        float* Wr  = sm;                       // 512 floats
        float* red = sm + 512;                 // 256 floats
        if (tid < 128)
            ((float4*)Wr)[tid] = ((const float4*)&Yop[(size_t)l * K_])[tid];
        __syncthreads();
        int b = tid & 127, seg = tid >> 7;     // 2 segs x 256 k
        int kb = seg * 256;
        float a0 = 0.f, a1 = 0.f, a2 = 0.f, a3 = 0.f;
#pragma unroll 4
        for (int kk = 0; kk < 256; kk += 4) {
            int k = kb + kk;
            a0 = fmaf(Wr[k + 0], sout[(k + 0) * B_ + b], a0);
            a1 = fmaf(Wr[k + 1], sout[(k + 1) * B_ + b], a1);
            a2 = fmaf(Wr[k + 2], sout[(k + 2) * B_ + b], a2);
            a3 = fmaf(Wr[k + 3], sout[(k + 3) * B_ + b], a3);
        }
        red[seg * 128 + b] = (a0 + a1) + (a2 + a3);
        __syncthreads();
        if (tid < 128)
            q[l * B_ + b] = red[b] + red[128 + b];
    }
}

// ========== L5 k_zfin: z10 = M8*q + U8*s -> zbT bf16 hi/lo [B][2K] ==========
__global__ __launch_bounds__(1024) void k_zfin(
        const float* __restrict__ M8, const float* __restrict__ U8,
        const float* __restrict__ q, const float* __restrict__ sout,
        unsigned short* __restrict__ zbT) {
    __shared__ __align__(16) float Wr[4 * K_];   // M8 row0,1 | U8 row0,1
    __shared__ float red[8][2][128];
    int tid = threadIdx.x;
    int l0 = blockIdx.x * 2;
    if (tid < 256)
        ((float4*)Wr)[tid] = ((const float4*)&M8[(size_t)l0 * K_])[tid];
    else if (tid < 512)
        ((float4*)&Wr[2 * K_])[tid - 256] =
            ((const float4*)&U8[(size_t)l0 * K_])[tid - 256];
    __syncthreads();
    int b = tid & 127, seg = tid >> 7;           // 8 segs x 64 k
    int kb = seg * 64;
    float a0m = 0.f, a0u = 0.f, a1m = 0.f, a1u = 0.f;
#pragma unroll 8
    for (int kk = 0; kk < 64; ++kk) {
        int k = kb + kk;
        float qv = q[k * B_ + b];
        float sv = sout[k * B_ + b];
        a0m = fmaf(Wr[k], qv, a0m);
        a0u = fmaf(Wr[2 * K_ + k], sv, a0u);
        a1m = fmaf(Wr[K_ + k], qv, a1m);
        a1u = fmaf(Wr[3 * K_ + k], sv, a1u);
    }
    red[seg][0][b] = a0m + a0u;
    red[seg][1][b] = a1m + a1u;
    __syncthreads();
    if (tid < 256) {
        int row = tid >> 7, bb = tid & 127;
        float t = 0.f;
#pragma unroll
        for (int u = 0; u < 8; ++u) t += red[u][row][bb];
        unsigned short hi = f2bf(t);
        unsigned short lo = f2bf(t - bf2f(hi));
        zbT[(size_t)bb * (2 * K_) + (l0 + row)]      = hi;   // hi plane
        zbT[(size_t)bb * (2 * K_) + K_ + (l0 + row)] = lo;   // lo plane
    }
}

// ========== L6 k_yg: y[b][g] = sum_k Mb[g][k]*(zhi+zlo)[k][b] + cvec[b] =====
__global__ __launch_bounds__(256) void k_yg(
        const unsigned short* __restrict__ Mb, const unsigned short* __restrict__ zbT,
        const float* __restrict__ cvec, float* __restrict__ y) {
    __shared__ __align__(16) unsigned short Al[128][72];
    __shared__ __align__(16) unsigned short Bh[128][72];
    __shared__ __align__(16) unsigned short Bl2[128][72];
    int tid = threadIdx.x;
    int g0 = blockIdx.x * 128;
    int wid = tid >> 6, lane = tid & 63;
    int wm = (wid >> 1) * 64, wn = (wid & 1) * 64;
    int r16 = lane & 15, kg8 = (lane >> 4) * 8;
    int ld_row = tid >> 3, ld_c8 = (tid & 7) * 8;
    f32x4 acc[4][4] = {};
    for (int kk = 0; kk < K_; kk += BKT) {
#pragma unroll
        for (int i = 0; i < 4; ++i) {
            int r = ld_row + 32 * i;
            *(uint4*)&Al[r][ld_c8] =
                *(const uint4*)&Mb[(size_t)(g0 + r) * K_ + kk + ld_c8];
            *(uint4*)&Bh[r][ld_c8] =
                *(const uint4*)&zbT[(size_t)r * (2 * K_) + kk + ld_c8];
            *(uint4*)&Bl2[r][ld_c8] =
                *(const uint4*)&zbT[(size_t)r * (2 * K_) + K_ + kk + ld_c8];
        }
        __syncthreads();
#pragma unroll
        for (int ks = 0; ks < 2; ++ks) {
            bf16x8 af[4], bh[4], bl[4];
#pragma unroll
            for (int mi = 0; mi < 4; ++mi)
                af[mi] = *(const bf16x8*)&Al[wm + mi * 16 + r16][ks * 32 + kg8];
#pragma unroll
            for (int ni = 0; ni < 4; ++ni) {
                bh[ni] = *(const bf16x8*)&Bh[wn + ni * 16 + r16][ks * 32 + kg8];
                bl[ni] = *(const bf16x8*)&Bl2[wn + ni * 16 + r16][ks * 32 + kg8];
            }
#pragma unroll
            for (int mi = 0; mi < 4; ++mi)
#pragma unroll
                for (int ni = 0; ni < 4; ++ni) {
                    acc[mi][ni] = __builtin_amdgcn_mfma_f32_16x16x32_bf16(
                        af[mi], bh[ni], acc[mi][ni], 0, 0, 0);
                    acc[mi][ni] = __builtin_amdgcn_mfma_f32_16x16x32_bf16(
                        af[mi], bl[ni], acc[mi][ni], 0, 0, 0);
                }
        }
        __syncthreads();
    }
    int cr = (lane >> 4) * 4, cc = lane & 15;
#pragma unroll
    for (int ni = 0; ni < 4; ++ni) {
        int b = wn + ni * 16 + cc;
        float cv = cvec[b];
#pragma unroll
        for (int mi = 0; mi < 4; ++mi) {
            int g = g0 + wm + mi * 16 + cr;
            if (g < G_) {                      // 4-aligned; whole float4 valid
                float4 o;
                o.x = acc[mi][ni][0] + cv;
                o.y = acc[mi][ni][1] + cv;
                o.z = acc[mi][ni][2] + cv;
                o.w = acc[mi][ni][3] + cv;
                *(float4*)&y[(size_t)b * G_ + g] = o;
            }
        }
    }
}

// ---------------------------------------------------------------------------
extern "C" void kernel_launch(void* const* d_in, const int* in_sizes, int n_in,
                              void* d_out, int out_size, void* d_ws, size_t ws_size,
                              hipStream_t stream) {
    const float* ctl   = (const float*)d_in[0];
    const float* dt    = (const float*)d_in[1];
    const int*   cidx  = (const int*)d_in[2];
    // d_in[3] = drug_fp (unused)
    const float* M     = (const float*)d_in[4];
    const float* A     = (const float*)d_in[5];
    const float* W_in  = (const float*)d_in[6];
    const float* b_in  = (const float*)d_in[7];
    const float* cemb  = (const float*)d_in[8];
    const float* W_out = (const float*)d_in[9];
    const float* b_out = (const float*)d_in[10];
    float* y = (float*)d_out;

    char* ws = (char*)d_ws;
    size_t o = 0;
    auto take = [&](size_t bytes) { char* p = ws + o; o = (o + bytes + 255) & ~(size_t)255; return p; };
    unsigned short* XpT = (unsigned short*)take((size_t)256 * GP * 2);  // 6.3 MB
    unsigned short* MTb = (unsigned short*)take((size_t)K_ * GP * 2);   // 12.6 MB
    unsigned short* Mb  = (unsigned short*)take((size_t)GP * K_ * 2);   // 12.6 MB
    unsigned short* zbT = (unsigned short*)take((size_t)B_ * 2 * K_ * 2); // 256 KB
    float* Cp   = (float*)take((size_t)NSEG * K_ * 256 * 4);            // 12.6 MB
    int*   deg  = (int*)  take(K_ * 4);
    float* cvec = (float*)take(B_ * 4);
    float* AT   = (float*)take((size_t)K_ * K_ * 4);                    // 1 MB each
    float* U2   = (float*)take((size_t)K_ * K_ * 4);
    float* M2   = (float*)take((size_t)K_ * K_ * 4);
    float* Yop  = (float*)take((size_t)K_ * K_ * 4);
    float* M4   = (float*)take((size_t)K_ * K_ * 4);
    float* U4   = (float*)take((size_t)K_ * K_ * 4);
    float* M8   = (float*)take((size_t)K_ * K_ * 4);
    float* U8   = (float*)take((size_t)K_ * K_ * 4);
    float* sout = (float*)take((size_t)K_ * B_ * 4);
    float* q    = (float*)take((size_t)K_ * B_ * 4);
    (void)ws_size; (void)in_sizes; (void)n_in; (void)out_size;

    // deg accumulates via integer atomics -> zero it every call (replay-safe)
    hipMemsetAsync(deg, 0, K_ * 4, stream);
    // L1: XpT hi pack + MTb/Mb 64x64 tiles + deg + AT/U2 + cvec
    k_pre<<<4865, 256, 0, stream>>>(ctl, dt, M, A, cidx, cemb, W_out, b_out,
                                    XpT, MTb, Mb, deg, AT, U2, cvec);
    // L2: split-K(24) MFMA GEMM (Cp) + P1 (M2, Yop)
    k_gemm<<<448, 256, 0, stream>>>(MTb, XpT, Cp, AT, U2, M2, Yop);
    // L3: reduce Cp + deg + MLP -> sout ; P2 (M4, U4)
    k_red<<<768, 256, 0, stream>>>(Cp, deg, W_in, b_in, W_out, sout,
                                   M2, U2, M4, U4);
    // L4: P3 (M8, U8) + panel q = Yop*s
    k_p3<<<1024, 256, 0, stream>>>(M4, U4, M8, U8, Yop, sout, q);
    // L5: z10 = M8*q + U8*s -> zbT bf16 hi/lo
    k_zfin<<<K_ / 2, 1024, 0, stream>>>(M8, U8, q, sout, zbT);
    // L6: y = Mb * (zhi + zlo) + cvec   (MFMA)
    k_yg<<<(G_ + 127) / 128, 256, 0, stream>>>(Mb, zbT, cvec, y);
}

// Round 11
// 98.728 us; speedup vs baseline: 1.1430x; 1.1430x over previous
//
#include <hip/hip_runtime.h>

// Problem constants (match reference)
#define B_    128
#define G_    12000
#define GP    12288     // G padded to 12*1024 (pad rows are zero => exact)
#define K_    512
#define H_    64
#define NSEG  24        // GEMM split-K segments
#define SEGG  512       // genes per segment
#define BKT   64        // GEMM K-step
#define NGT   192       // M g-tiles (64 rows each)

typedef __attribute__((ext_vector_type(8))) short bf16x8;
typedef __attribute__((ext_vector_type(4))) float f32x4;

__device__ __forceinline__ unsigned short f2bf(float x) {
    union { float f; unsigned u; } v; v.f = x;
    unsigned r = (v.u + 0x7FFFu + ((v.u >> 16) & 1u)) >> 16;
    return (unsigned short)r;
}
__device__ __forceinline__ float bf2f(unsigned short b) {
    union { float f; unsigned u; } v; v.u = ((unsigned)b) << 16;
    return v.f;
}

// ---------------- mm body: O = alpha*Aop*Bop + beta*Cop; opt O2 = O + Dop ---
__device__ __forceinline__ void mm_body(int k0, int l0, float* __restrict__ sm,
        const float* __restrict__ Aop, const float* __restrict__ Bop,
        const float* __restrict__ Cop, const float* __restrict__ Dop,
        float alpha, float beta, float* __restrict__ O, float* __restrict__ O2) {
    float (*Xa)[68] = (float(*)[68])sm;              // 32*68
    float (*Xb)[36] = (float(*)[36])(sm + 2176);     // 64*36
    int tid = threadIdx.x;
    int kg = tid & 15, lg = tid >> 4;
    float acc[2][2] = {};
    for (int jj = 0; jj < K_; jj += 64) {
#pragma unroll
        for (int i = 0; i < 2; ++i) {
            int lin = tid + i * 256;
            int r = lin >> 4, c4 = lin & 15;
            *(float4*)&Xa[r][c4 * 4] =
                *(const float4*)&Aop[(size_t)(l0 + r) * K_ + jj + c4 * 4];
        }
#pragma unroll
        for (int i = 0; i < 2; ++i) {
            int lin = tid + i * 256;
            int r = lin >> 3, c4 = lin & 7;
            *(float4*)&Xb[r][c4 * 4] =
                *(const float4*)&Bop[(size_t)(jj + r) * K_ + k0 + c4 * 4];
        }
        __syncthreads();
#pragma unroll 8
        for (int j = 0; j < 64; ++j) {
            float xa0 = Xa[lg * 2][j], xa1 = Xa[lg * 2 + 1][j];
            float xb0 = Xb[j][kg * 2], xb1 = Xb[j][kg * 2 + 1];
            acc[0][0] = fmaf(xa0, xb0, acc[0][0]);
            acc[0][1] = fmaf(xa0, xb1, acc[0][1]);
            acc[1][0] = fmaf(xa1, xb0, acc[1][0]);
            acc[1][1] = fmaf(xa1, xb1, acc[1][1]);
        }
        __syncthreads();
    }
#pragma unroll
    for (int i = 0; i < 2; ++i) {
        size_t idx = (size_t)(l0 + lg * 2 + i) * K_ + k0 + kg * 2;
        float2 v;
        v.x = alpha * acc[i][0];
        v.y = alpha * acc[i][1];
        if (beta != 0.0f) {
            float2 cc = *(const float2*)&Cop[idx];
            v.x = fmaf(beta, cc.x, v.x);
            v.y = fmaf(beta, cc.y, v.y);
        }
        *(float2*)&O[idx] = v;
        if (O2) {
            float2 dd = *(const float2*)&Dop[idx];
            float2 w2; w2.x = v.x + dd.x; w2.y = v.y + dd.y;
            *(float2*)&O2[idx] = w2;
        }
    }
}

// ---------------- panel body: out[l][b] = sum_k W[l][k] * src[k][b] ---------
__device__ __forceinline__ void panel_body(int l, float* __restrict__ sm,
        const float* __restrict__ W, const float* __restrict__ src,
        float* __restrict__ out) {
    float* Wr  = sm;                       // 512 floats
    float* red = sm + 512;                 // 256 floats
    int tid = threadIdx.x;
    if (tid < 128)
        ((float4*)Wr)[tid] = ((const float4*)&W[(size_t)l * K_])[tid];
    __syncthreads();
    int b = tid & 127, seg = tid >> 7;     // 2 segs x 256 k
    int kb = seg * 256;
    float a0 = 0.f, a1 = 0.f, a2 = 0.f, a3 = 0.f;
#pragma unroll 4
    for (int kk = 0; kk < 256; kk += 4) {
        int k = kb + kk;
        a0 = fmaf(Wr[k + 0], src[(k + 0) * B_ + b], a0);
        a1 = fmaf(Wr[k + 1], src[(k + 1) * B_ + b], a1);
        a2 = fmaf(Wr[k + 2], src[(k + 2) * B_ + b], a2);
        a3 = fmaf(Wr[k + 3], src[(k + 3) * B_ + b], a3);
    }
    red[seg * 128 + b] = (a0 + a1) + (a2 + a3);
    __syncthreads();
    if (tid < 128)
        out[l * B_ + b] = red[b] + red[128 + b];
}

// ========== L1 k_pre: {XpT bf16 | MTb+Mb 64x64 tiles + pdeg | AT,U2 | cvec} =
__global__ __launch_bounds__(256) void k_pre(
        const float* __restrict__ ctl, const float* __restrict__ dt,
        const float* __restrict__ M, const float* __restrict__ A,
        const int* __restrict__ cidx, const float* __restrict__ cemb,
        const float* __restrict__ W_out, const float* __restrict__ b_out,
        unsigned short* __restrict__ XpT, unsigned short* __restrict__ MTb,
        unsigned short* __restrict__ Mb, int* __restrict__ pdeg,
        float* __restrict__ AT, float* __restrict__ U2,
        float* __restrict__ cvec) {
    int bid = blockIdx.x, tid = threadIdx.x;
    if (bid < 3072) {                          // XpT hi plane: 256 rows x GP
        int p = bid / 12, chunk = bid % 12;
        int ch = p >> 7, b = p & 127;
        const float* src = (ch ? dt : ctl) + (size_t)b * G_;
        int g = chunk * 1024 + tid * 4;
        float x0 = 0.f, x1 = 0.f, x2 = 0.f, x3 = 0.f;
        if (g + 3 < G_) {
            float4 v = *(const float4*)&src[g];
            x0 = v.x; x1 = v.y; x2 = v.z; x3 = v.w;
        } else {
            if (g + 0 < G_) x0 = src[g + 0];
            if (g + 1 < G_) x1 = src[g + 1];
            if (g + 2 < G_) x2 = src[g + 2];
            if (g + 3 < G_) x3 = src[g + 3];
        }
        ushort4 hv;
        hv.x = f2bf(x0); hv.y = f2bf(x1); hv.z = f2bf(x2); hv.w = f2bf(x3);
        *(ushort4*)&XpT[(size_t)p * GP + g] = hv;
    } else if (bid < 4608) {                   // M 64x64 tile: Mb + MTb + pdeg
        __shared__ float t[64][65];
        __shared__ int csum[4][64];
        int id = bid - 3072;                   // 0..1535
        int gt = id % NGT, kt = id / NGT;      // 192 g-tiles x 8 k-tiles
        int g0 = gt * 64, k0 = kt * 64;
        int tx = tid & 63, ty = tid >> 6;      // 64 x 4
        int cnt = 0;
#pragma unroll
        for (int j = 0; j < 16; ++j) {
            int g = g0 + ty + 4 * j;
            float v = (g < G_) ? M[(size_t)g * K_ + k0 + tx] : 0.0f;
            t[ty + 4 * j][tx] = v;
            Mb[(size_t)g * K_ + k0 + tx] = f2bf(v);
            cnt += (v != 0.0f);
        }
        csum[ty][tx] = cnt;
        __syncthreads();
        if (ty == 0)
            pdeg[(size_t)(k0 + tx) * NGT + gt] =
                csum[0][tx] + csum[1][tx] + csum[2][tx] + csum[3][tx];
#pragma unroll
        for (int j = 0; j < 16; ++j)
            MTb[(size_t)(k0 + ty + 4 * j) * GP + g0 + tx] =
                f2bf(t[tx][ty + 4 * j]);
    } else if (bid < 4864) {                   // AT + U2 = 0.09*AT + 0.1*I
        __shared__ float t[32][33];
        int id = bid - 4608;
        int x0 = (id & 15) * 32, y0 = (id >> 4) * 32;
        int tx = tid & 31, ty = tid >> 5;
#pragma unroll
        for (int j = 0; j < 4; ++j)
            t[ty + 8 * j][tx] = A[(size_t)(y0 + ty + 8 * j) * K_ + x0 + tx];
        __syncthreads();
#pragma unroll
        for (int j = 0; j < 4; ++j) {
            int row = x0 + ty + 8 * j, col = y0 + tx;
            float v = t[tx][ty + 8 * j];
            AT[(size_t)row * K_ + col] = v;
            U2[(size_t)row * K_ + col] = 0.09f * v + (row == col ? 0.1f : 0.0f);
        }
    } else {                                   // cvec
        if (tid < B_) {
            int ci = cidx[tid];
            float acc = b_out[0];
#pragma unroll 8
            for (int h = 0; h < H_; ++h)
                acc = fmaf(cemb[ci * H_ + h], W_out[h], acc);
            cvec[tid] = acc;
        }
    }
}

// ========== L2 k_gemm: {Cp[seg] = MTb*XpT^T (MFMA, split-K 24) | P1 mm} =====
__global__ __launch_bounds__(256) void k_gemm(
        const unsigned short* __restrict__ MTb, const unsigned short* __restrict__ XpT,
        float* __restrict__ Cp,
        const float* __restrict__ AT, const float* __restrict__ U2,
        float* __restrict__ M2, float* __restrict__ Yop) {
    __shared__ __align__(16) char smraw[36864];
    int bid = blockIdx.x, tid = threadIdx.x;
    if (bid < 192) {
        unsigned short (*Al)[72] = (unsigned short(*)[72])smraw;
        unsigned short (*Bl)[72] = (unsigned short(*)[72])(smraw + 18432);
        int tile = bid & 7, seg = bid >> 3;
        int m0 = (tile & 3) * 128, n0 = (tile >> 2) * 128;
        size_t gbase = (size_t)seg * SEGG;
        int wid = tid >> 6, lane = tid & 63;
        int wm = (wid >> 1) * 64, wn = (wid & 1) * 64;
        int r16 = lane & 15, kg8 = (lane >> 4) * 8;
        int ld_row = tid >> 3, ld_c8 = (tid & 7) * 8;
        f32x4 acc[4][4] = {};
        for (int kk = 0; kk < SEGG; kk += BKT) {
#pragma unroll
            for (int i = 0; i < 4; ++i) {
                int r = ld_row + 32 * i;
                *(uint4*)&Al[r][ld_c8] =
                    *(const uint4*)&MTb[(size_t)(m0 + r) * GP + gbase + kk + ld_c8];
                *(uint4*)&Bl[r][ld_c8] =
                    *(const uint4*)&XpT[(size_t)(n0 + r) * GP + gbase + kk + ld_c8];
            }
            __syncthreads();
#pragma unroll
            for (int ks = 0; ks < 2; ++ks) {
                bf16x8 af[4], bf[4];
#pragma unroll
                for (int mi = 0; mi < 4; ++mi)
                    af[mi] = *(const bf16x8*)&Al[wm + mi * 16 + r16][ks * 32 + kg8];
#pragma unroll
                for (int ni = 0; ni < 4; ++ni)
                    bf[ni] = *(const bf16x8*)&Bl[wn + ni * 16 + r16][ks * 32 + kg8];
#pragma unroll
                for (int mi = 0; mi < 4; ++mi)
#pragma unroll
                    for (int ni = 0; ni < 4; ++ni)
                        acc[mi][ni] = __builtin_amdgcn_mfma_f32_16x16x32_bf16(
                            af[mi], bf[ni], acc[mi][ni], 0, 0, 0);
            }
            __syncthreads();
        }
        float* C = Cp + (size_t)seg * (K_ * 256);
        int cr = (lane >> 4) * 4, cc = lane & 15;
#pragma unroll
        for (int mi = 0; mi < 4; ++mi)
#pragma unroll
            for (int ni = 0; ni < 4; ++ni) {
                size_t rb = (size_t)(m0 + wm + mi * 16 + cr) * 256
                          + (n0 + wn + ni * 16 + cc);
#pragma unroll
                for (int r = 0; r < 4; ++r)
                    C[rb + (size_t)r * 256] = acc[mi][ni][r];
            }
    } else {                                   // P1: M2 = 0.81*AT*AT; Yop = M2+U2
        int id = bid - 192;
        mm_body((id & 15) * 32, (id >> 4) * 32, (float*)smraw,
                AT, AT, nullptr, U2, 0.81f, 0.0f, M2, Yop);
    }
}

// ========== L3 k_red: {reduce Cp + deg (pdeg reduce) + MLP | P2: M4, U4} ====
__global__ __launch_bounds__(256) void k_red(
        const float* __restrict__ Cp, const int* __restrict__ pdeg,
        const float* __restrict__ W_in, const float* __restrict__ b_in,
        const float* __restrict__ W_out, float* __restrict__ sout,
        const float* __restrict__ M2, const float* __restrict__ U2,
        float* __restrict__ M4, float* __restrict__ U4) {
    __shared__ __align__(16) float sm[4480];
    int bid = blockIdx.x, tid = threadIdx.x;
    if (bid < 256) {
        int kloc = tid >> 7, b = tid & 127;
        int k = bid * 2 + kloc;
        // deg: coalesced 2-value read + wave/LDS reduce
        int v = 0;
        if (b < 96)
            v = pdeg[(size_t)k * NGT + b] + pdeg[(size_t)k * NGT + 96 + b];
#pragma unroll
        for (int off = 32; off; off >>= 1) v += __shfl_down(v, off, 64);
        __shared__ int dsum[4];
        __shared__ float degs[2];
        if ((tid & 63) == 0) dsum[tid >> 6] = v;
        __syncthreads();
        if (tid < 2) degs[tid] = (float)(dsum[tid * 2] + dsum[tid * 2 + 1]);
        __syncthreads();
        float x0 = 0.f, x1 = 0.f;
#pragma unroll 4
        for (int s = 0; s < NSEG; ++s) {
            const float* Cb = Cp + (size_t)s * (K_ * 256) + (size_t)k * 256;
            x0 += Cb[b];
            x1 += Cb[128 + b];
        }
        float inv = 1.0f / fmaxf(degs[kloc], 1.0f);
        x0 *= inv; x1 *= inv;
        float s = 0.f;
#pragma unroll 8
        for (int h = 0; h < H_; ++h) {
            float vv = fmaf(x0, W_in[h], fmaf(x1, W_in[H_ + h], b_in[h]));
            vv = fmaxf(vv, 0.f);
            s = fmaf(vv, W_out[h], s);
        }
        sout[k * B_ + b] = s;
    } else {                                   // P2: M4 = M2*M2; U4 = M2*U2+U2
        int id = bid - 256;
        int t = id & 255;
        if (id < 256)
            mm_body((t & 15) * 32, (t >> 4) * 32, sm, M2, M2, nullptr, nullptr,
                    1.0f, 0.0f, M4, nullptr);
        else
            mm_body((t & 15) * 32, (t >> 4) * 32, sm, M2, U2, U2, nullptr,
                    1.0f, 1.0f, U4, nullptr);
    }
}

// ========== L4 k_p3: {M8 = M4*M4 | q = Yop*s | bb = U4*s} ===================
__global__ __launch_bounds__(256) void k_p3(
        const float* __restrict__ M4, const float* __restrict__ U4,
        float* __restrict__ M8,
        const float* __restrict__ Yop, const float* __restrict__ sout,
        float* __restrict__ q, float* __restrict__ bb) {
    __shared__ __align__(16) float sm[4480];
    int bid = blockIdx.x;
    if (bid < 256) {
        mm_body((bid & 15) * 32, (bid >> 4) * 32, sm, M4, M4, nullptr, nullptr,
                1.0f, 0.0f, M8, nullptr);
    } else if (bid < 768) {
        panel_body(bid - 256, sm, Yop, sout, q);
    } else {
        panel_body(bid - 768, sm, U4, sout, bb);
    }
}

// ========== L5 k_zfin: z10 = M8*q + M4*bb + bb -> zbT bf16 hi/lo [B][2K] ====
__global__ __launch_bounds__(1024) void k_zfin(
        const float* __restrict__ M8, const float* __restrict__ M4,
        const float* __restrict__ q, const float* __restrict__ bb,
        unsigned short* __restrict__ zbT) {
    __shared__ __align__(16) float Wr[4 * K_];   // M8 row0,1 | M4 row0,1
    __shared__ float red[8][2][128];
    int tid = threadIdx.x;
    int l0 = blockIdx.x * 2;
    if (tid < 256)
        ((float4*)Wr)[tid] = ((const float4*)&M8[(size_t)l0 * K_])[tid];
    else if (tid < 512)
        ((float4*)&Wr[2 * K_])[tid - 256] =
            ((const float4*)&M4[(size_t)l0 * K_])[tid - 256];
    __syncthreads();
    int b = tid & 127, seg = tid >> 7;           // 8 segs x 64 k
    int kb = seg * 64;
    float a0m = 0.f, a0u = 0.f, a1m = 0.f, a1u = 0.f;
#pragma unroll 8
    for (int kk = 0; kk < 64; ++kk) {
        int k = kb + kk;
        float qv = q[k * B_ + b];
        float bv = bb[k * B_ + b];
        a0m = fmaf(Wr[k], qv, a0m);
        a0u = fmaf(Wr[2 * K_ + k], bv, a0u);
        a1m = fmaf(Wr[K_ + k], qv, a1m);
        a1u = fmaf(Wr[3 * K_ + k], bv, a1u);
    }
    red[seg][0][b] = a0m + a0u;
    red[seg][1][b] = a1m + a1u;
    __syncthreads();
    if (tid < 256) {
        int row = tid >> 7, bi = tid & 127;
        float t = bb[(l0 + row) * B_ + bi];      // + I*bb term
#pragma unroll
        for (int u = 0; u < 8; ++u) t += red[u][row][bi];
        unsigned short hi = f2bf(t);
        unsigned short lo = f2bf(t - bf2f(hi));
        zbT[(size_t)bi * (2 * K_) + (l0 + row)]      = hi;
        zbT[(size_t)bi * (2 * K_) + K_ + (l0 + row)] = lo;
    }
}

// ========== L6 k_yg: y = Mb*(zhi+zlo) + cvec  (64-row tiles, 188 blocks) ====
__global__ __launch_bounds__(256) void k_yg(
        const unsigned short* __restrict__ Mb, const unsigned short* __restrict__ zbT,
        const float* __restrict__ cvec, float* __restrict__ y) {
    __shared__ __align__(16) unsigned short Al[64][72];
    __shared__ __align__(16) unsigned short Bh[128][72];
    __shared__ __align__(16) unsigned short Bl2[128][72];
    int tid = threadIdx.x;
    int g0 = blockIdx.x * 64;
    int wid = tid >> 6, lane = tid & 63;
    int wm = (wid >> 1) * 32, wn = (wid & 1) * 64;    // waves: 2m x 2n
    int r16 = lane & 15, kg8 = (lane >> 4) * 8;
    int ld_row = tid >> 3, ld_c8 = (tid & 7) * 8;
    f32x4 acc[2][4] = {};
    for (int kk = 0; kk < K_; kk += BKT) {
#pragma unroll
        for (int i = 0; i < 2; ++i) {
            int r = ld_row + 32 * i;
            *(uint4*)&Al[r][ld_c8] =
                *(const uint4*)&Mb[(size_t)(g0 + r) * K_ + kk + ld_c8];
        }
#pragma unroll
        for (int i = 0; i < 4; ++i) {
            int r = ld_row + 32 * i;
            *(uint4*)&Bh[r][ld_c8] =
                *(const uint4*)&zbT[(size_t)r * (2 * K_) + kk + ld_c8];
            *(uint4*)&Bl2[r][ld_c8] =
                *(const uint4*)&zbT[(size_t)r * (2 * K_) + K_ + kk + ld_c8];
        }
        __syncthreads();
#pragma unroll
        for (int ks = 0; ks < 2; ++ks) {
            bf16x8 af[2], bh[4], bl[4];
#pragma unroll
            for (int mi = 0; mi < 2; ++mi)
                af[mi] = *(const bf16x8*)&Al[wm + mi * 16 + r16][ks * 32 + kg8];
#pragma unroll
            for (int ni = 0; ni < 4; ++ni) {
                bh[ni] = *(const bf16x8*)&Bh[wn + ni * 16 + r16][ks * 32 + kg8];
                bl[ni] = *(const bf16x8*)&Bl2[wn + ni * 16 + r16][ks * 32 + kg8];
            }
#pragma unroll
            for (int mi = 0; mi < 2; ++mi)
#pragma unroll
                for (int ni = 0; ni < 4; ++ni) {
                    acc[mi][ni] = __builtin_amdgcn_mfma_f32_16x16x32_bf16(
                        af[mi], bh[ni], acc[mi][ni], 0, 0, 0);
                    acc[mi][ni] = __builtin_amdgcn_mfma_f32_16x16x32_bf16(
                        af[mi], bl[ni], acc[mi][ni], 0, 0, 0);
                }
        }
        __syncthreads();
    }
    int cr = (lane >> 4) * 4, cc = lane & 15;
#pragma unroll
    for (int ni = 0; ni < 4; ++ni) {
        int b = wn + ni * 16 + cc;
        float cv = cvec[b];
#pragma unroll
        for (int mi = 0; mi < 2; ++mi) {
            int g = g0 + wm + mi * 16 + cr;
            if (g < G_) {                      // g multiple of 4; float4 valid
                float4 o;
                o.x = acc[mi][ni][0] + cv;
                o.y = acc[mi][ni][1] + cv;
                o.z = acc[mi][ni][2] + cv;
                o.w = acc[mi][ni][3] + cv;
                *(float4*)&y[(size_t)b * G_ + g] = o;
            }
        }
    }
}

// ---------------------------------------------------------------------------
extern "C" void kernel_launch(void* const* d_in, const int* in_sizes, int n_in,
                              void* d_out, int out_size, void* d_ws, size_t ws_size,
                              hipStream_t stream) {
    const float* ctl   = (const float*)d_in[0];
    const float* dt    = (const float*)d_in[1];
    const int*   cidx  = (const int*)d_in[2];
    // d_in[3] = drug_fp (unused)
    const float* M     = (const float*)d_in[4];
    const float* A     = (const float*)d_in[5];
    const float* W_in  = (const float*)d_in[6];
    const float* b_in  = (const float*)d_in[7];
    const float* cemb  = (const float*)d_in[8];
    const float* W_out = (const float*)d_in[9];
    const float* b_out = (const float*)d_in[10];
    float* y = (float*)d_out;

    char* ws = (char*)d_ws;
    size_t o = 0;
    auto take = [&](size_t bytes) { char* p = ws + o; o = (o + bytes + 255) & ~(size_t)255; return p; };
    unsigned short* XpT = (unsigned short*)take((size_t)256 * GP * 2);  // 6.3 MB
    unsigned short* MTb = (unsigned short*)take((size_t)K_ * GP * 2);   // 12.6 MB
    unsigned short* Mb  = (unsigned short*)take((size_t)GP * K_ * 2);   // 12.6 MB
    unsigned short* zbT = (unsigned short*)take((size_t)B_ * 2 * K_ * 2); // 256 KB
    float* Cp   = (float*)take((size_t)NSEG * K_ * 256 * 4);            // 12.6 MB
    int*   pdeg = (int*)  take((size_t)K_ * NGT * 4);                   // 393 KB
    float* cvec = (float*)take(B_ * 4);
    float* AT   = (float*)take((size_t)K_ * K_ * 4);                    // 1 MB each
    float* U2   = (float*)take((size_t)K_ * K_ * 4);
    float* M2   = (float*)take((size_t)K_ * K_ * 4);
    float* Yop  = (float*)take((size_t)K_ * K_ * 4);
    float* M4   = (float*)take((size_t)K_ * K_ * 4);
    float* U4   = (float*)take((size_t)K_ * K_ * 4);
    float* M8   = (float*)take((size_t)K_ * K_ * 4);
    float* sout = (float*)take((size_t)K_ * B_ * 4);
    float* q    = (float*)take((size_t)K_ * B_ * 4);
    float* bb   = (float*)take((size_t)K_ * B_ * 4);
    (void)ws_size; (void)in_sizes; (void)n_in; (void)out_size;

    // L1: XpT pack + MTb/Mb tiles + pdeg partials (no atomics) + AT/U2 + cvec
    k_pre<<<4865, 256, 0, stream>>>(ctl, dt, M, A, cidx, cemb, W_out, b_out,
                                    XpT, MTb, Mb, pdeg, AT, U2, cvec);
    // L2: split-K(24) MFMA GEMM (Cp) + P1 (M2, Yop)
    k_gemm<<<448, 256, 0, stream>>>(MTb, XpT, Cp, AT, U2, M2, Yop);
    // L3: reduce Cp + deg + MLP -> sout ; P2 (M4, U4)
    k_red<<<768, 256, 0, stream>>>(Cp, pdeg, W_in, b_in, W_out, sout,
                                   M2, U2, M4, U4);
    // L4: M8 = M4*M4 ; q = Yop*s ; bb = U4*s
    k_p3<<<1280, 256, 0, stream>>>(M4, U4, M8, Yop, sout, q, bb);
    // L5: z10 = M8*q + M4*bb + bb -> zbT bf16 hi/lo
    k_zfin<<<K_ / 2, 1024, 0, stream>>>(M8, M4, q, bb, zbT);
    // L6: y = Mb*(zhi+zlo) + cvec   (MFMA, 188 blocks)
    k_yg<<<(G_ + 63) / 64, 256, 0, stream>>>(Mb, zbT, cvec, y);
}